// Round 10
// baseline (993.879 us; speedup 1.0000x reference)
//
#include <hip/hip_runtime.h>

// Fully fused quantized encoder, MFMA edition — 512-thread (8-wave) blocks.
// GEMMs: D[oc][frame] = W^T · act, bf16 hi/lo split (3 MFMAs, al*bl dropped ~2^-18).
// Weights pre-packed into d_ws in MFMA A-frag stream order (pack_w kernel).
// Activations live in LDS in MFMA B-frag stream order (hi 16KB + lo 16KB).
// This rev: r9 showed VALU cut (48->38%) with flat time -> limiter is phase
// serialization (16 barriers/pass + LDS round-trips), not VALU. Changes:
//  (1) barrier audit: pass-top, G3->E3, G6->E6 syncs removed (protected
//      targets are >=4 barriers back; B-frag WAR still enforced by kept
//      after-E3 / after-E6 barriers). 16 -> 12 barriers/pass.
//  (2) S1+S1b fused: each thread computes its 16 rotated frames PLUS both
//      boundary frames (identical formula -> identical bits) into bf16-
//      rounded registers (rotated slot order keeps all indices compile-time;
//      cndmask selects for wrap). Kills the ci1 LDS round-trip + 1 barrier.
// Bit-identical throughout (absmax==4.0 is the canary).
// Retained: 512thr/2blk/CU, pass-local weight loads via volatile-zero offset,
// gemm unroll-1, E3 mt-outer/k-inner, S4 LUT requant, E3->E6 resf handoff
// through r2 ring, nontemporal fx4 out stores, cvt_pk_bf16_f32.

#define CIN   256
#define LOUT  120000
#define TIN   600000
#define FB    128
#define NBLK  ((LOUT + FB - 1) / FB)   // 938

typedef float fx4 __attribute__((ext_vector_type(4)));
typedef short bx8 __attribute__((ext_vector_type(8)));

// ---- LDS map ----
#define BF_OFF   0        // 32768 B: B-frags (32 frames x 256 k), hi + lo bf16
#define CI1_OFF  32768    // (free since r10 — ci1 now lives in registers)
#define R2R_OFF  50176    //  9880 B: r2 ring, 38 slots x 260 B (stride 260 = bank spread)
#define C3R_OFF  60056    // 13000 B: c3 ring, 50 slots x 260 B
#define XW_OFF   73056    //   704 B: x window (176 floats)
#define LUT_OFF  73760    //   256 B: S4 dequant->requant int8 LUT
#define LDS_SZ   74016

__device__ __forceinline__ float lrelu(float v){ return v >= 0.0f ? v : 0.3f*v; }
__device__ __forceinline__ float clip8(float v){ return fminf(fmaxf(v, -128.0f), 127.0f); }
__device__ __forceinline__ unsigned short f2bf(float f){
  unsigned u = __builtin_bit_cast(unsigned, f);
  return (unsigned short)((u + 0x7FFFu + ((u >> 16) & 1u)) >> 16);  // RNE
}
__device__ __forceinline__ float bf2f(unsigned short h){
  unsigned u = ((unsigned)h) << 16;
  return __builtin_bit_cast(float, u);
}
// HW packed f32->bf16 (RNE, same result as f2bf): dst.lo=bf16(a), dst.hi=bf16(b)
__device__ __forceinline__ unsigned cvtpk(float a, float b){
  unsigned r;
  asm("v_cvt_pk_bf16_f32 %0, %1, %2" : "=v"(r) : "v"(a), "v"(b));
  return r;
}

// GEMM: acc[mt][nt] += Wmat-tile x B-act-tile, 3-term hi/lo split.
// Per-wave tile: M=32 (2 x 16-oc sub-tiles), N=32 frames, K=256.
// unroll 1: keeps live fragments ~32 VGPRs (fits the 64-arch-VGPR split).
__device__ __forceinline__ void gemm_mfma(const char* __restrict__ Aw,
                                          const char* __restrict__ Bf,
                                          int lofs, fx4 acc[2][2])
{
#pragma unroll 1
  for (int kk = 0; kk < 8; ++kk) {
    bx8 Bh0 = *(const bx8*)(Bf + kk*4096 +        lofs);
    bx8 Bl0 = *(const bx8*)(Bf + kk*4096 + 1024 + lofs);
    bx8 Bh1 = *(const bx8*)(Bf + kk*4096 + 2048 + lofs);
    bx8 Bl1 = *(const bx8*)(Bf + kk*4096 + 3072 + lofs);
#pragma unroll
    for (int mt = 0; mt < 2; ++mt) {
      bx8 Ah = *(const bx8*)(Aw + (mt*8 + kk)*2048 +        lofs);
      bx8 Al = *(const bx8*)(Aw + (mt*8 + kk)*2048 + 1024 + lofs);
      acc[mt][0] = __builtin_amdgcn_mfma_f32_16x16x32_bf16(Ah, Bh0, acc[mt][0], 0, 0, 0);
      acc[mt][0] = __builtin_amdgcn_mfma_f32_16x16x32_bf16(Al, Bh0, acc[mt][0], 0, 0, 0);
      acc[mt][0] = __builtin_amdgcn_mfma_f32_16x16x32_bf16(Ah, Bl0, acc[mt][0], 0, 0, 0);
      acc[mt][1] = __builtin_amdgcn_mfma_f32_16x16x32_bf16(Ah, Bh1, acc[mt][1], 0, 0, 0);
      acc[mt][1] = __builtin_amdgcn_mfma_f32_16x16x32_bf16(Al, Bh1, acc[mt][1], 0, 0, 0);
      acc[mt][1] = __builtin_amdgcn_mfma_f32_16x16x32_bf16(Ah, Bl1, acc[mt][1], 0, 0, 0);
    }
  }
}

// Pack 6 weight matrices [ic][oc] into A-frag stream (hi+lo bf16) in d_ws.
__global__ void pack_w(const float* __restrict__ w0, const float* __restrict__ w1,
                       const float* __restrict__ w2, const float* __restrict__ w3,
                       const float* __restrict__ w4, const float* __restrict__ w5,
                       char* __restrict__ Apk)
{
  const int l = blockIdx.x*256 + threadIdx.x;          // < 49152
  const int lane = l & 63, kk = (l >> 6) & 7, wm = (l >> 9) & 15, mat = l >> 13;
  const float* W = mat==0?w0 : mat==1?w1 : mat==2?w2 : mat==3?w3 : mat==4?w4 : w5;
  const int oc = wm*16 + (lane & 15);
  const int k0 = kk*32 + (lane >> 4)*8;
  unsigned short h[8], lo[8];
#pragma unroll
  for (int j = 0; j < 8; ++j) {
    const float v = W[(k0 + j)*CIN + oc];
    h[j]  = f2bf(v);
    lo[j] = f2bf(v - bf2f(h[j]));
  }
  char* base = Apk + mat*262144 + (wm*8 + kk)*2048 + lane*16;
  *(ushort4*)(base)        = make_ushort4(h[0],  h[1],  h[2],  h[3]);
  *(ushort4*)(base + 8)    = make_ushort4(h[4],  h[5],  h[6],  h[7]);
  *(ushort4*)(base + 1024) = make_ushort4(lo[0], lo[1], lo[2], lo[3]);
  *(ushort4*)(base + 1032) = make_ushort4(lo[4], lo[5], lo[6], lo[7]);
}

__launch_bounds__(512, 4)
__global__ void enc_kernel(const float* __restrict__ x,
                           const char* __restrict__ Apk,
                           const float* __restrict__ w_first, const float* __restrict__ b_first,
                           const float* __restrict__ w_dw1, const float* __restrict__ b_dw1,
                           const float* __restrict__ b_pw1, const float* __restrict__ b_lc1,
                           const float* __restrict__ w_dw2, const float* __restrict__ b_dw2,
                           const float* __restrict__ b_pw2, const float* __restrict__ b_lc2,
                           const float* __restrict__ w_dw3, const float* __restrict__ b_dw3,
                           const float* __restrict__ b_pw3, const float* __restrict__ b_lc3,
                           float* __restrict__ out)
{
  __shared__ __align__(16) char lds[LDS_SZ];
  const int tid  = threadIdx.x;        // 0..511
  const int lane = tid & 63;
  const int wv   = tid >> 6;           // 0..7
  const int qq   = lane >> 4;
  const int nn   = lane & 15;
  const int lofs = lane * 16;
  const int ch   = tid & 255;          // channel for S-phases
  const int hf   = tid >> 8;           // frame-half (0/1)
  const int rot  = tid & 15;           // frame rotation (bank spread)
  const int t0   = blockIdx.x * FB;
  const fx4 fz = {0.0f, 0.0f, 0.0f, 0.0f};
  const char* Awv = Apk + wv*32768;    // per-wave A base (32 oc slice)

  // LICM blocker: volatile zero, re-read each pass. Compiler cannot prove
  // z==0, so any load whose address involves z stays inside the pass loop.
  volatile int vz = 0;

  // S4 dequant->requant LUT: pure function of the ring int8; computed with
  // the EXACT op sequence S4 used inline -> bit-identical. Written once;
  // >=2 barriers precede the first S4 read.
  if (tid < 256) {
    const float r  = (float)(tid - 128);
    const float dq = (lrelu(r) + 47.0f) * 5.548006534576416f;
    const float c  = clip8(rintf(dq / 5.548006534576416f - 47.0f));
    *(signed char*)&lds[LUT_OFF + tid] = (signed char)(int)c;
  }

  // frag-write constants for channel c = ch (k-dim position)
  const int wofs_c = (ch >> 5)*4096 + (((ch & 31) >> 3)*16)*16 + (ch & 7)*2;

  int c0m[2];
#pragma unroll
  for (int mt = 0; mt < 2; ++mt) c0m[mt] = wv*32 + mt*16 + qq*4;

  fx4 acc[2][2];

  for (int pass = 0; pass < 5; ++pass) {
    const int pt0 = t0 - 32 + pass*32;
    const int xbase = 5*pt0 - 15;

    const int z = vz;                  // fresh opaque 0 each pass
    const float* wfq  = w_first + z; const float* bfq  = b_first + z;
    const float* wd1q = w_dw1 + z;   const float* bd1q = b_dw1 + z;
    const float* wd2q = w_dw2 + z;   const float* bd2q = b_dw2 + z;
    const float* wd3q = w_dw3 + z;   const float* bd3q = b_dw3 + z;
    const float* bp1q = b_pw1 + z;   const float* bl1q = b_lc1 + z;
    const float* bp2q = b_pw2 + z;   const float* bl2q = b_lc2 + z;
    const float* bp3q = b_pw3 + z;   const float* bl3q = b_lc3 + z;

    // resf lives E6 -> G9 only (E3's value is re-read from the r2 LDS ring).
    float resf[2][2][4];

    // (pass-top sync removed: xw-sync below orders G9_prev B-reads vs S1
    // B-writes; all other prev-pass readers are >=4 barriers back)
    if (tid < 176) {
      const int gx = xbase + tid;
      *(float*)&lds[XW_OFF + tid*4] = (gx >= 0 && gx < TIN) ? x[gx] : 0.0f;
    }
    __syncthreads();

    // ---- S1+S1b fused: first conv + leaky -> ci regs (bf16-rounded),
    //      dw1 (dil 1) -> B-frags. Rotated register order keeps the bank-
    //      spread write pattern with compile-time register indices.
    //      c[u] holds frame hf*16 + ((u+rot)&15); cb0/cb1 = frames +16/+17
    //      (identical formula as the original cross-thread values). ----
    {
      float wf[10];
#pragma unroll
      for (int k = 0; k < 10; ++k) wf[k] = wfq[k*CIN + ch];
      const float bfv = bfq[ch];
      float c[16], cb0, cb1;
#pragma unroll
      for (int u = 0; u < 16; ++u) {
        const int j = hf*16 + ((u + rot) & 15);
        float a = 0.0f;
#pragma unroll
        for (int k = 0; k < 10; ++k)
          a = fmaf(*(const float*)&lds[XW_OFF + (5*j + k)*4], wf[k], a);
        const float ci = (pt0 + j - 2 < 0) ? 0.0f : lrelu(a + bfv);
        c[u] = __builtin_bit_cast(float, cvtpk(ci, ci) << 16);
      }
#pragma unroll
      for (int b = 0; b < 2; ++b) {
        const int j = hf*16 + 16 + b;
        float a = 0.0f;
#pragma unroll
        for (int k = 0; k < 10; ++k)
          a = fmaf(*(const float*)&lds[XW_OFF + (5*j + k)*4], wf[k], a);
        const float ci = (pt0 + j - 2 < 0) ? 0.0f : lrelu(a + bfv);
        const float cv = __builtin_bit_cast(float, cvtpk(ci, ci) << 16);
        if (b == 0) cb0 = cv; else cb1 = cv;
      }
      const float d10 = wd1q[ch], d11 = wd1q[CIN+ch], d12 = wd1q[2*CIN+ch];
      const float bd1 = bd1q[ch];
#pragma unroll
      for (int s = 0; s < 16; ++s) {
        const int jloc = (s + rot) & 15;
        const int jr = hf*16 + jloc;
        const float c2 = c[s];
        const float c1 = (jloc == 15) ? cb0 : c[(s + 1) & 15];
        const float c0 = (jloc == 15) ? cb1 :
                         ((jloc == 14) ? cb0 : c[(s + 2) & 15]);
        const float v = fmaf(d10, c2, fmaf(d11, c1, fmaf(d12, c0, bd1)));
        const int ab = wofs_c + ((jr >> 4)*2048) + ((jr & 15)*16);
        const unsigned hp = cvtpk(v, v);
        const float hb = __builtin_bit_cast(float, hp << 16);
        const unsigned lp = cvtpk(v - hb, v - hb);
        *(unsigned short*)&lds[BF_OFF + ab]        = (unsigned short)hp;
        *(unsigned short*)&lds[BF_OFF + ab + 1024] = (unsigned short)lp;
      }
    }
    __syncthreads();

    // ---- G2: pw1 ----
#pragma unroll
    for (int mt = 0; mt < 2; ++mt) { acc[mt][0] = fz; acc[mt][1] = fz; }
    gemm_mfma(Awv + 0*262144, (const char*)lds + BF_OFF, lofs, acc);
    __syncthreads();
    // E2: +bias, quantize(17.63,-67), leaky -> B-frags
#pragma unroll
    for (int mt = 0; mt < 2; ++mt) {
      const int c0 = c0m[mt];
      const float4 bb = *(const float4*)&bp1q[c0];
      const float bbv[4] = {bb.x, bb.y, bb.z, bb.w};
      const int ab0 = (c0 >> 5)*4096 + (((c0 & 31) >> 3)*16 + nn)*16 + (c0 & 7)*2;
#pragma unroll
      for (int nt = 0; nt < 2; ++nt) {
        float av[4];
#pragma unroll
        for (int r = 0; r < 4; ++r) {
          const float h  = acc[mt][nt][r] + bbv[r];
          const float qv = clip8(rintf(h / 17.62967872619629f + 67.0f));
          av[r] = lrelu(qv);
        }
        const unsigned h01 = cvtpk(av[0], av[1]);
        const unsigned h23 = cvtpk(av[2], av[3]);
        const float hb0 = __builtin_bit_cast(float, h01 << 16);
        const float hb1 = __builtin_bit_cast(float, h01 & 0xFFFF0000u);
        const float hb2 = __builtin_bit_cast(float, h23 << 16);
        const float hb3 = __builtin_bit_cast(float, h23 & 0xFFFF0000u);
        const unsigned l01 = cvtpk(av[0]-hb0, av[1]-hb1);
        const unsigned l23 = cvtpk(av[2]-hb2, av[3]-hb3);
        const int ab = ab0 + nt*2048;
        *(uint2*)&lds[BF_OFF + ab]        = make_uint2(h01, h23);
        *(uint2*)&lds[BF_OFF + ab + 1024] = make_uint2(l01, l23);
      }
    }
    __syncthreads();

    // ---- G3: lc1 ----
#pragma unroll
    for (int mt = 0; mt < 2; ++mt) { acc[mt][0] = fz; acc[mt][1] = fz; }
    gemm_mfma(Awv + 1*262144, (const char*)lds + BF_OFF, lofs, acc);
    // (G3->E3 sync removed: E3 touches only the r2 ring, whose prior-pass
    // readers are >=5 barriers back; S4's B-frag WAR is the after-E3 sync)
    // E3: ro1 dequant + r1(recompute, mt-outer/k-inner) -> quantize -> r2 ring
#pragma unroll
    for (int mt = 0; mt < 2; ++mt) {
      const int c0 = c0m[mt];
      float r10[4] = {0.0f, 0.0f, 0.0f, 0.0f};   // nt=0 accumulators
      float r11[4] = {0.0f, 0.0f, 0.0f, 0.0f};   // nt=1 accumulators
#pragma unroll 2
      for (int k = 0; k < 10; ++k) {
        const float4 wk = *(const float4*)&wfq[k*CIN + c0];
        const float x0 = *(const float*)&lds[XW_OFF + (5*nn        + 10 + k)*4];
        const float x1 = *(const float*)&lds[XW_OFF + (5*(16 + nn) + 10 + k)*4];
        r10[0] = fmaf(x0, wk.x, r10[0]); r10[1] = fmaf(x0, wk.y, r10[1]);
        r10[2] = fmaf(x0, wk.z, r10[2]); r10[3] = fmaf(x0, wk.w, r10[3]);
        r11[0] = fmaf(x1, wk.x, r11[0]); r11[1] = fmaf(x1, wk.y, r11[1]);
        r11[2] = fmaf(x1, wk.z, r11[2]); r11[3] = fmaf(x1, wk.w, r11[3]);
      }
      const float4 bl = *(const float4*)&bl1q[c0];
      const float4 bf = *(const float4*)&bfq[c0];
      const float blv[4] = {bl.x, bl.y, bl.z, bl.w};
      const float bfa[4] = {bf.x, bf.y, bf.z, bf.w};
      // nt = 0
      {
        const int t = pt0 + nn;
        const int slot = (t + 3800) % 38;
        int pk = 0;
#pragma unroll
        for (int r = 0; r < 4; ++r) {
          const float ro1 = (acc[mt][0][r] + blv[r] - 16.0f) * 6.528060436248779f;
          const float v   = (r10[r] + bfa[r]) + ro1;
          const float q   = clip8(rintf(v / 12.716455459594727f + 23.0f));
          pk |= ((int)q & 255) << (8*r);
        }
        *(int*)&lds[R2R_OFF + slot*260 + c0] = pk;
      }
      // nt = 1
      {
        const int t = pt0 + 16 + nn;
        const int slot = (t + 3800) % 38;
        int pk = 0;
#pragma unroll
        for (int r = 0; r < 4; ++r) {
          const float ro1 = (acc[mt][1][r] + blv[r] - 16.0f) * 6.528060436248779f;
          const float v   = (r11[r] + bfa[r]) + ro1;
          const float q   = clip8(rintf(v / 12.716455459594727f + 23.0f));
          pk |= ((int)q & 255) << (8*r);
        }
        *(int*)&lds[R2R_OFF + slot*260 + c0] = pk;
      }
    }
    __syncthreads();

    // ---- S4: dw2 (dil 3) from r2 ring -> B-frags (LUT requant) ----
    {
      const float d20 = wd2q[ch], d21 = wd2q[CIN+ch], d22 = wd2q[2*CIN+ch];
      const float bd2 = bd2q[ch];
      for (int s = 0; s < 16; ++s) {
        const int jr = hf*16 + ((s + tid) & 15);
        const int t = pt0 + jr;
        float cv[3];
#pragma unroll
        for (int li = 0; li < 3; ++li) {
          const int tt = t - 3*(2 - li);          // lags 6, 3, 0
          float c;
          if (tt < 0) c = -47.0f;
          else {
            const int sl = (tt + 3800) % 38;
            const int rv = (int)*(const signed char*)&lds[R2R_OFF + sl*260 + ch];
            c = (float)*(const signed char*)&lds[LUT_OFF + 128 + rv];
          }
          cv[li] = c;
        }
        const float v = fmaf(d20, cv[0], fmaf(d21, cv[1], fmaf(d22, cv[2], bd2)));
        const int ab = wofs_c + ((jr >> 4)*2048) + ((jr & 15)*16);
        const unsigned hp = cvtpk(v, v);
        const float hb = __builtin_bit_cast(float, hp << 16);
        const unsigned lp = cvtpk(v - hb, v - hb);
        *(unsigned short*)&lds[BF_OFF + ab]        = (unsigned short)hp;
        *(unsigned short*)&lds[BF_OFF + ab + 1024] = (unsigned short)lp;
      }
    }
    __syncthreads();

    // ---- G5: pw2 ----
#pragma unroll
    for (int mt = 0; mt < 2; ++mt) { acc[mt][0] = fz; acc[mt][1] = fz; }
    gemm_mfma(Awv + 2*262144, (const char*)lds + BF_OFF, lofs, acc);
    __syncthreads();
    // E5: +bias, leaky -> B-frags
#pragma unroll
    for (int mt = 0; mt < 2; ++mt) {
      const int c0 = c0m[mt];
      const float4 bb = *(const float4*)&bp2q[c0];
      const float bbv[4] = {bb.x, bb.y, bb.z, bb.w};
      const int ab0 = (c0 >> 5)*4096 + (((c0 & 31) >> 3)*16 + nn)*16 + (c0 & 7)*2;
#pragma unroll
      for (int nt = 0; nt < 2; ++nt) {
        float av[4];
#pragma unroll
        for (int r = 0; r < 4; ++r)
          av[r] = lrelu(acc[mt][nt][r] + bbv[r]);
        const unsigned h01 = cvtpk(av[0], av[1]);
        const unsigned h23 = cvtpk(av[2], av[3]);
        const float hb0 = __builtin_bit_cast(float, h01 << 16);
        const float hb1 = __builtin_bit_cast(float, h01 & 0xFFFF0000u);
        const float hb2 = __builtin_bit_cast(float, h23 << 16);
        const float hb3 = __builtin_bit_cast(float, h23 & 0xFFFF0000u);
        const unsigned l01 = cvtpk(av[0]-hb0, av[1]-hb1);
        const unsigned l23 = cvtpk(av[2]-hb2, av[3]-hb3);
        const int ab = ab0 + nt*2048;
        *(uint2*)&lds[BF_OFF + ab]        = make_uint2(h01, h23);
        *(uint2*)&lds[BF_OFF + ab + 1024] = make_uint2(l01, l23);
      }
    }
    __syncthreads();

    // ---- G6: lc2 ----
#pragma unroll
    for (int mt = 0; mt < 2; ++mt) { acc[mt][0] = fz; acc[mt][1] = fz; }
    gemm_mfma(Awv + 3*262144, (const char*)lds + BF_OFF, lofs, acc);
    // (G6->E6 sync removed: E6 writes only the c3 ring, whose prior-pass
    // reader S7 is >=4 barriers back; S7's B-frag WAR is the after-E6 sync)
    // E6: r3 = ro2 + q(re-read from r2 ring) -> resf; ci3 quant -> c3 ring
#pragma unroll
    for (int nt = 0; nt < 2; ++nt) {
      const int t = pt0 + nt*16 + nn;
      const int slot  = (t + 5000) % 50;
      const int slot2 = (t + 3800) % 38;
#pragma unroll
      for (int mt = 0; mt < 2; ++mt) {
        const int c0 = c0m[mt];
        const int pk2 = *(const int*)&lds[R2R_OFF + slot2*260 + c0];  // own E3 write
        const float4 bl = *(const float4*)&bl2q[c0];
        const float blv[4] = {bl.x, bl.y, bl.z, bl.w};
        int pk = 0;
#pragma unroll
        for (int r = 0; r < 4; ++r) {
          const float qold = (float)((signed char)((pk2 >> (8*r)) & 255));
          const float r3 = (acc[mt][nt][r] + blv[r]) + qold;
          resf[mt][nt][r] = r3;
          const float dq = (lrelu(r3) + 38.0f) * 4.458680152893066f;
          const float q  = clip8(rintf(dq / 4.458680152893066f - 38.0f));
          pk |= ((int)q & 255) << (8*r);
        }
        *(int*)&lds[C3R_OFF + slot*260 + c0] = pk;
      }
    }
    __syncthreads();

    if (pass == 0) continue;

    // ---- S7: dw3 (dil 9) from c3 ring -> B-frags ----
    {
      const float d30 = wd3q[ch], d31 = wd3q[CIN+ch], d32 = wd3q[2*CIN+ch];
      const float bd3 = bd3q[ch];
      for (int s = 0; s < 16; ++s) {
        const int jr = hf*16 + ((s + tid) & 15);
        const int t = pt0 + jr;
        float cv[3];
#pragma unroll
        for (int li = 0; li < 3; ++li) {
          const int tt = t - 9*(2 - li);          // lags 18, 9, 0
          float c;
          if (tt < 0) c = -38.0f;
          else {
            const int sl = (tt + 5000) % 50;
            c = (float)*(const signed char*)&lds[C3R_OFF + sl*260 + ch];
          }
          cv[li] = c;
        }
        const float v = fmaf(d30, cv[0], fmaf(d31, cv[1], fmaf(d32, cv[2], bd3)));
        const int ab = wofs_c + ((jr >> 4)*2048) + ((jr & 15)*16);
        const unsigned hp = cvtpk(v, v);
        const float hb = __builtin_bit_cast(float, hp << 16);
        const unsigned lp = cvtpk(v - hb, v - hb);
        *(unsigned short*)&lds[BF_OFF + ab]        = (unsigned short)hp;
        *(unsigned short*)&lds[BF_OFF + ab + 1024] = (unsigned short)lp;
      }
    }
    __syncthreads();

    // ---- G8: pw3 ----
#pragma unroll
    for (int mt = 0; mt < 2; ++mt) { acc[mt][0] = fz; acc[mt][1] = fz; }
    gemm_mfma(Awv + 4*262144, (const char*)lds + BF_OFF, lofs, acc);
    __syncthreads();
    // E8: +bias, leaky -> B-frags
#pragma unroll
    for (int mt = 0; mt < 2; ++mt) {
      const int c0 = c0m[mt];
      const float4 bb = *(const float4*)&bp3q[c0];
      const float bbv[4] = {bb.x, bb.y, bb.z, bb.w};
      const int ab0 = (c0 >> 5)*4096 + (((c0 & 31) >> 3)*16 + nn)*16 + (c0 & 7)*2;
#pragma unroll
      for (int nt = 0; nt < 2; ++nt) {
        float av[4];
#pragma unroll
        for (int r = 0; r < 4; ++r)
          av[r] = lrelu(acc[mt][nt][r] + bbv[r]);
        const unsigned h01 = cvtpk(av[0], av[1]);
        const unsigned h23 = cvtpk(av[2], av[3]);
        const float hb0 = __builtin_bit_cast(float, h01 << 16);
        const float hb1 = __builtin_bit_cast(float, h01 & 0xFFFF0000u);
        const float hb2 = __builtin_bit_cast(float, h23 << 16);
        const float hb3 = __builtin_bit_cast(float, h23 & 0xFFFF0000u);
        const unsigned l01 = cvtpk(av[0]-hb0, av[1]-hb1);
        const unsigned l23 = cvtpk(av[2]-hb2, av[3]-hb3);
        const int ab = ab0 + nt*2048;
        *(uint2*)&lds[BF_OFF + ab]        = make_uint2(h01, h23);
        *(uint2*)&lds[BF_OFF + ab + 1024] = make_uint2(l01, l23);
      }
    }
    __syncthreads();

    // ---- G9: lc3 + final epilogue -> out (nontemporal: write-once stream) ----
#pragma unroll
    for (int mt = 0; mt < 2; ++mt) { acc[mt][0] = fz; acc[mt][1] = fz; }
    gemm_mfma(Awv + 5*262144, (const char*)lds + BF_OFF, lofs, acc);
#pragma unroll
    for (int nt = 0; nt < 2; ++nt) {
      const int t = pt0 + nt*16 + nn;
      if (t < LOUT) {
#pragma unroll
        for (int mt = 0; mt < 2; ++mt) {
          const int c0 = c0m[mt];
          const float4 bl = *(const float4*)&bl3q[c0];
          const float blv[4] = {bl.x, bl.y, bl.z, bl.w};
          fx4 o;
#pragma unroll
          for (int r = 0; r < 4; ++r) {
            const float r4 = (acc[mt][nt][r] + blv[r]) + resf[mt][nt][r];
            o[r] = (lrelu(r4) + 34.0f) * 3.698859930038452f;
          }
          __builtin_nontemporal_store(o, (fx4*)&out[t*CIN + c0]);
        }
      }
    }
  }
}

extern "C" void kernel_launch(void* const* d_in, const int* in_sizes, int n_in,
                              void* d_out, int out_size, void* d_ws, size_t ws_size,
                              hipStream_t stream) {
  (void)in_sizes; (void)n_in; (void)out_size; (void)ws_size;
  const float* x       = (const float*)d_in[0];
  const float* w_first = (const float*)d_in[5];
  const float* b_first = (const float*)d_in[6];
  const float* w_dw1   = (const float*)d_in[7];
  const float* b_dw1   = (const float*)d_in[8];
  const float* w_pw1   = (const float*)d_in[9];
  const float* b_pw1   = (const float*)d_in[10];
  const float* w_lc1   = (const float*)d_in[11];
  const float* b_lc1   = (const float*)d_in[12];
  const float* w_dw2   = (const float*)d_in[13];
  const float* b_dw2   = (const float*)d_in[14];
  const float* w_pw2   = (const float*)d_in[15];
  const float* b_pw2   = (const float*)d_in[16];
  const float* w_lc2   = (const float*)d_in[17];
  const float* b_lc2   = (const float*)d_in[18];
  const float* w_dw3   = (const float*)d_in[19];
  const float* b_dw3   = (const float*)d_in[20];
  const float* w_pw3   = (const float*)d_in[21];
  const float* b_pw3   = (const float*)d_in[22];
  const float* w_lc3   = (const float*)d_in[23];
  const float* b_lc3   = (const float*)d_in[24];

  char* Apk = (char*)d_ws;                       // 6 x 262144 B = 1.5 MB

  pack_w<<<dim3(192), dim3(256), 0, stream>>>(w_pw1, w_lc1, w_pw2, w_lc2, w_pw3, w_lc3, Apk);
  enc_kernel<<<dim3(NBLK), dim3(512), 0, stream>>>(
      x, Apk, w_first, b_first,
      w_dw1, b_dw1, b_pw1, b_lc1,
      w_dw2, b_dw2, b_pw2, b_lc2,
      w_dw3, b_dw3, b_pw3, b_lc3,
      (float*)d_out);
}

// Round 11
// 761.581 us; speedup vs baseline: 1.3050x; 1.3050x over previous
//
#include <hip/hip_runtime.h>

// Fully fused quantized encoder, MFMA edition — 512-thread (8-wave) blocks.
// GEMMs: D[oc][frame] = W^T · act, bf16 hi/lo split (3 MFMAs, al*bl dropped ~2^-18).
// Weights pre-packed into d_ws in MFMA A-frag stream order (pack_w kernel).
// Activations live in LDS in MFMA B-frag stream order (hi 16KB + lo 16KB).
// r10 lesson (3rd confirmation): under the 64+64 arch/AGPR split, any S/E
// phase gaining >~10 live registers spills (S1-fusion's c[16]+wf[10] ->
// FETCH 237->624MB, dur 727->901us). This rev reverts the fusion (ci1 back
// through LDS, r9 form) and KEEPS the three audited barrier removals
// (pass-top, G3->E3, G6->E6 — zero register cost, correctness-verified):
// 13 barriers/pass vs r9's 16.
// Retained: 512thr/2blk/CU, pass-local weight loads via volatile-zero offset,
// gemm unroll-1, E3 mt-outer/k-inner, S4 LUT requant, E3->E6 resf handoff
// through r2 ring, nontemporal fx4 out stores, cvt_pk_bf16_f32.

#define CIN   256
#define LOUT  120000
#define TIN   600000
#define FB    128
#define NBLK  ((LOUT + FB - 1) / FB)   // 938

typedef float fx4 __attribute__((ext_vector_type(4)));
typedef short bx8 __attribute__((ext_vector_type(8)));

// ---- LDS map ----
#define BF_OFF   0        // 32768 B: B-frags (32 frames x 256 k), hi + lo bf16
#define CI1_OFF  32768    // 17408 B: ci1 bf16 [c][34]
#define R2R_OFF  50176    //  9880 B: r2 ring, 38 slots x 260 B (stride 260 = bank spread)
#define C3R_OFF  60056    // 13000 B: c3 ring, 50 slots x 260 B
#define XW_OFF   73056    //   704 B: x window (176 floats)
#define LUT_OFF  73760    //   256 B: S4 dequant->requant int8 LUT
#define LDS_SZ   74016

__device__ __forceinline__ float lrelu(float v){ return v >= 0.0f ? v : 0.3f*v; }
__device__ __forceinline__ float clip8(float v){ return fminf(fmaxf(v, -128.0f), 127.0f); }
__device__ __forceinline__ unsigned short f2bf(float f){
  unsigned u = __builtin_bit_cast(unsigned, f);
  return (unsigned short)((u + 0x7FFFu + ((u >> 16) & 1u)) >> 16);  // RNE
}
__device__ __forceinline__ float bf2f(unsigned short h){
  unsigned u = ((unsigned)h) << 16;
  return __builtin_bit_cast(float, u);
}
// HW packed f32->bf16 (RNE, same result as f2bf): dst.lo=bf16(a), dst.hi=bf16(b)
__device__ __forceinline__ unsigned cvtpk(float a, float b){
  unsigned r;
  asm("v_cvt_pk_bf16_f32 %0, %1, %2" : "=v"(r) : "v"(a), "v"(b));
  return r;
}

// GEMM: acc[mt][nt] += Wmat-tile x B-act-tile, 3-term hi/lo split.
// Per-wave tile: M=32 (2 x 16-oc sub-tiles), N=32 frames, K=256.
// unroll 1: keeps live fragments ~32 VGPRs (fits the 64-arch-VGPR split).
__device__ __forceinline__ void gemm_mfma(const char* __restrict__ Aw,
                                          const char* __restrict__ Bf,
                                          int lofs, fx4 acc[2][2])
{
#pragma unroll 1
  for (int kk = 0; kk < 8; ++kk) {
    bx8 Bh0 = *(const bx8*)(Bf + kk*4096 +        lofs);
    bx8 Bl0 = *(const bx8*)(Bf + kk*4096 + 1024 + lofs);
    bx8 Bh1 = *(const bx8*)(Bf + kk*4096 + 2048 + lofs);
    bx8 Bl1 = *(const bx8*)(Bf + kk*4096 + 3072 + lofs);
#pragma unroll
    for (int mt = 0; mt < 2; ++mt) {
      bx8 Ah = *(const bx8*)(Aw + (mt*8 + kk)*2048 +        lofs);
      bx8 Al = *(const bx8*)(Aw + (mt*8 + kk)*2048 + 1024 + lofs);
      acc[mt][0] = __builtin_amdgcn_mfma_f32_16x16x32_bf16(Ah, Bh0, acc[mt][0], 0, 0, 0);
      acc[mt][0] = __builtin_amdgcn_mfma_f32_16x16x32_bf16(Al, Bh0, acc[mt][0], 0, 0, 0);
      acc[mt][0] = __builtin_amdgcn_mfma_f32_16x16x32_bf16(Ah, Bl0, acc[mt][0], 0, 0, 0);
      acc[mt][1] = __builtin_amdgcn_mfma_f32_16x16x32_bf16(Ah, Bh1, acc[mt][1], 0, 0, 0);
      acc[mt][1] = __builtin_amdgcn_mfma_f32_16x16x32_bf16(Al, Bh1, acc[mt][1], 0, 0, 0);
      acc[mt][1] = __builtin_amdgcn_mfma_f32_16x16x32_bf16(Ah, Bl1, acc[mt][1], 0, 0, 0);
    }
  }
}

// Pack 6 weight matrices [ic][oc] into A-frag stream (hi+lo bf16) in d_ws.
__global__ void pack_w(const float* __restrict__ w0, const float* __restrict__ w1,
                       const float* __restrict__ w2, const float* __restrict__ w3,
                       const float* __restrict__ w4, const float* __restrict__ w5,
                       char* __restrict__ Apk)
{
  const int l = blockIdx.x*256 + threadIdx.x;          // < 49152
  const int lane = l & 63, kk = (l >> 6) & 7, wm = (l >> 9) & 15, mat = l >> 13;
  const float* W = mat==0?w0 : mat==1?w1 : mat==2?w2 : mat==3?w3 : mat==4?w4 : w5;
  const int oc = wm*16 + (lane & 15);
  const int k0 = kk*32 + (lane >> 4)*8;
  unsigned short h[8], lo[8];
#pragma unroll
  for (int j = 0; j < 8; ++j) {
    const float v = W[(k0 + j)*CIN + oc];
    h[j]  = f2bf(v);
    lo[j] = f2bf(v - bf2f(h[j]));
  }
  char* base = Apk + mat*262144 + (wm*8 + kk)*2048 + lane*16;
  *(ushort4*)(base)        = make_ushort4(h[0],  h[1],  h[2],  h[3]);
  *(ushort4*)(base + 8)    = make_ushort4(h[4],  h[5],  h[6],  h[7]);
  *(ushort4*)(base + 1024) = make_ushort4(lo[0], lo[1], lo[2], lo[3]);
  *(ushort4*)(base + 1032) = make_ushort4(lo[4], lo[5], lo[6], lo[7]);
}

__launch_bounds__(512, 4)
__global__ void enc_kernel(const float* __restrict__ x,
                           const char* __restrict__ Apk,
                           const float* __restrict__ w_first, const float* __restrict__ b_first,
                           const float* __restrict__ w_dw1, const float* __restrict__ b_dw1,
                           const float* __restrict__ b_pw1, const float* __restrict__ b_lc1,
                           const float* __restrict__ w_dw2, const float* __restrict__ b_dw2,
                           const float* __restrict__ b_pw2, const float* __restrict__ b_lc2,
                           const float* __restrict__ w_dw3, const float* __restrict__ b_dw3,
                           const float* __restrict__ b_pw3, const float* __restrict__ b_lc3,
                           float* __restrict__ out)
{
  __shared__ __align__(16) char lds[LDS_SZ];
  const int tid  = threadIdx.x;        // 0..511
  const int lane = tid & 63;
  const int wv   = tid >> 6;           // 0..7
  const int qq   = lane >> 4;
  const int nn   = lane & 15;
  const int lofs = lane * 16;
  const int ch   = tid & 255;          // channel for S-phases
  const int hf   = tid >> 8;           // frame-half (0/1)
  const int t0   = blockIdx.x * FB;
  const fx4 fz = {0.0f, 0.0f, 0.0f, 0.0f};
  const char* Awv = Apk + wv*32768;    // per-wave A base (32 oc slice)

  // LICM blocker: volatile zero, re-read each pass. Compiler cannot prove
  // z==0, so any load whose address involves z stays inside the pass loop.
  volatile int vz = 0;

  // S4 dequant->requant LUT: pure function of the ring int8; computed with
  // the EXACT op sequence S4 used inline -> bit-identical. Written once;
  // >=2 barriers precede the first S4 read.
  if (tid < 256) {
    const float r  = (float)(tid - 128);
    const float dq = (lrelu(r) + 47.0f) * 5.548006534576416f;
    const float c  = clip8(rintf(dq / 5.548006534576416f - 47.0f));
    *(signed char*)&lds[LUT_OFF + tid] = (signed char)(int)c;
  }

  // frag-write constants for channel c = ch (k-dim position)
  const int wofs_c = (ch >> 5)*4096 + (((ch & 31) >> 3)*16)*16 + (ch & 7)*2;

  int c0m[2];
#pragma unroll
  for (int mt = 0; mt < 2; ++mt) c0m[mt] = wv*32 + mt*16 + qq*4;

  fx4 acc[2][2];

  for (int pass = 0; pass < 5; ++pass) {
    const int pt0 = t0 - 32 + pass*32;
    const int xbase = 5*pt0 - 15;

    const int z = vz;                  // fresh opaque 0 each pass
    const float* wfq  = w_first + z; const float* bfq  = b_first + z;
    const float* wd1q = w_dw1 + z;   const float* bd1q = b_dw1 + z;
    const float* wd2q = w_dw2 + z;   const float* bd2q = b_dw2 + z;
    const float* wd3q = w_dw3 + z;   const float* bd3q = b_dw3 + z;
    const float* bp1q = b_pw1 + z;   const float* bl1q = b_lc1 + z;
    const float* bp2q = b_pw2 + z;   const float* bl2q = b_lc2 + z;
    const float* bp3q = b_pw3 + z;   const float* bl3q = b_lc3 + z;

    // resf lives E6 -> G9 only (E3's value is re-read from the r2 LDS ring).
    float resf[2][2][4];

    // (pass-top sync removed: xw-sync below orders G9_prev B-reads vs S1b
    // B-writes — two barriers before those writes; all other prev-pass
    // readers of xw/ci1 are >=4 barriers back)
    if (tid < 176) {
      const int gx = xbase + tid;
      *(float*)&lds[XW_OFF + tid*4] = (gx >= 0 && gx < TIN) ? x[gx] : 0.0f;
    }
    __syncthreads();

    // ---- S1: first conv + leaky -> ci1 (bf16); halves split j 0..16 / 17..33 ----
    {
      float wf[10];
#pragma unroll
      for (int k = 0; k < 10; ++k) wf[k] = wfq[k*CIN + ch];
      const float bfv = bfq[ch];
      const int j0 = hf * 17;
      for (int j = j0; j < j0 + 17; ++j) {
        const int t = pt0 + j - 2;
        float a = 0.0f;
#pragma unroll
        for (int k = 0; k < 10; ++k)
          a = fmaf(*(const float*)&lds[XW_OFF + (5*j + k)*4], wf[k], a);
        const float ci = (t < 0) ? 0.0f : lrelu(a + bfv);
        *(unsigned short*)&lds[CI1_OFF + (ch*34 + j)*2] = (unsigned short)cvtpk(ci, ci);
      }
    }
    __syncthreads();

    // ---- S1b: dw1 (dil 1) -> B-frags; halves split frames 0..15 / 16..31 ----
    {
      const float d10 = wd1q[ch], d11 = wd1q[CIN+ch], d12 = wd1q[2*CIN+ch];
      const float bd1 = bd1q[ch];
      for (int s = 0; s < 16; ++s) {
        const int jr = hf*16 + ((s + tid) & 15);
        const float c2 = bf2f(*(const unsigned short*)&lds[CI1_OFF + (ch*34 + jr    )*2]);
        const float c1 = bf2f(*(const unsigned short*)&lds[CI1_OFF + (ch*34 + jr + 1)*2]);
        const float c0 = bf2f(*(const unsigned short*)&lds[CI1_OFF + (ch*34 + jr + 2)*2]);
        const float v = fmaf(d10, c2, fmaf(d11, c1, fmaf(d12, c0, bd1)));
        const int ab = wofs_c + ((jr >> 4)*2048) + ((jr & 15)*16);
        const unsigned hp = cvtpk(v, v);
        const float hb = __builtin_bit_cast(float, hp << 16);
        const unsigned lp = cvtpk(v - hb, v - hb);
        *(unsigned short*)&lds[BF_OFF + ab]        = (unsigned short)hp;
        *(unsigned short*)&lds[BF_OFF + ab + 1024] = (unsigned short)lp;
      }
    }
    __syncthreads();

    // ---- G2: pw1 ----
#pragma unroll
    for (int mt = 0; mt < 2; ++mt) { acc[mt][0] = fz; acc[mt][1] = fz; }
    gemm_mfma(Awv + 0*262144, (const char*)lds + BF_OFF, lofs, acc);
    __syncthreads();
    // E2: +bias, quantize(17.63,-67), leaky -> B-frags
#pragma unroll
    for (int mt = 0; mt < 2; ++mt) {
      const int c0 = c0m[mt];
      const float4 bb = *(const float4*)&bp1q[c0];
      const float bbv[4] = {bb.x, bb.y, bb.z, bb.w};
      const int ab0 = (c0 >> 5)*4096 + (((c0 & 31) >> 3)*16 + nn)*16 + (c0 & 7)*2;
#pragma unroll
      for (int nt = 0; nt < 2; ++nt) {
        float av[4];
#pragma unroll
        for (int r = 0; r < 4; ++r) {
          const float h  = acc[mt][nt][r] + bbv[r];
          const float qv = clip8(rintf(h / 17.62967872619629f + 67.0f));
          av[r] = lrelu(qv);
        }
        const unsigned h01 = cvtpk(av[0], av[1]);
        const unsigned h23 = cvtpk(av[2], av[3]);
        const float hb0 = __builtin_bit_cast(float, h01 << 16);
        const float hb1 = __builtin_bit_cast(float, h01 & 0xFFFF0000u);
        const float hb2 = __builtin_bit_cast(float, h23 << 16);
        const float hb3 = __builtin_bit_cast(float, h23 & 0xFFFF0000u);
        const unsigned l01 = cvtpk(av[0]-hb0, av[1]-hb1);
        const unsigned l23 = cvtpk(av[2]-hb2, av[3]-hb3);
        const int ab = ab0 + nt*2048;
        *(uint2*)&lds[BF_OFF + ab]        = make_uint2(h01, h23);
        *(uint2*)&lds[BF_OFF + ab + 1024] = make_uint2(l01, l23);
      }
    }
    __syncthreads();

    // ---- G3: lc1 ----
#pragma unroll
    for (int mt = 0; mt < 2; ++mt) { acc[mt][0] = fz; acc[mt][1] = fz; }
    gemm_mfma(Awv + 1*262144, (const char*)lds + BF_OFF, lofs, acc);
    // (G3->E3 sync removed: E3 touches only the r2 ring, whose prior-pass
    // readers are >=5 barriers back; S4's B-frag WAR is the after-E3 sync)
    // E3: ro1 dequant + r1(recompute, mt-outer/k-inner) -> quantize -> r2 ring
#pragma unroll
    for (int mt = 0; mt < 2; ++mt) {
      const int c0 = c0m[mt];
      float r10[4] = {0.0f, 0.0f, 0.0f, 0.0f};   // nt=0 accumulators
      float r11[4] = {0.0f, 0.0f, 0.0f, 0.0f};   // nt=1 accumulators
#pragma unroll 2
      for (int k = 0; k < 10; ++k) {
        const float4 wk = *(const float4*)&wfq[k*CIN + c0];
        const float x0 = *(const float*)&lds[XW_OFF + (5*nn        + 10 + k)*4];
        const float x1 = *(const float*)&lds[XW_OFF + (5*(16 + nn) + 10 + k)*4];
        r10[0] = fmaf(x0, wk.x, r10[0]); r10[1] = fmaf(x0, wk.y, r10[1]);
        r10[2] = fmaf(x0, wk.z, r10[2]); r10[3] = fmaf(x0, wk.w, r10[3]);
        r11[0] = fmaf(x1, wk.x, r11[0]); r11[1] = fmaf(x1, wk.y, r11[1]);
        r11[2] = fmaf(x1, wk.z, r11[2]); r11[3] = fmaf(x1, wk.w, r11[3]);
      }
      const float4 bl = *(const float4*)&bl1q[c0];
      const float4 bf = *(const float4*)&bfq[c0];
      const float blv[4] = {bl.x, bl.y, bl.z, bl.w};
      const float bfa[4] = {bf.x, bf.y, bf.z, bf.w};
      // nt = 0
      {
        const int t = pt0 + nn;
        const int slot = (t + 3800) % 38;
        int pk = 0;
#pragma unroll
        for (int r = 0; r < 4; ++r) {
          const float ro1 = (acc[mt][0][r] + blv[r] - 16.0f) * 6.528060436248779f;
          const float v   = (r10[r] + bfa[r]) + ro1;
          const float q   = clip8(rintf(v / 12.716455459594727f + 23.0f));
          pk |= ((int)q & 255) << (8*r);
        }
        *(int*)&lds[R2R_OFF + slot*260 + c0] = pk;
      }
      // nt = 1
      {
        const int t = pt0 + 16 + nn;
        const int slot = (t + 3800) % 38;
        int pk = 0;
#pragma unroll
        for (int r = 0; r < 4; ++r) {
          const float ro1 = (acc[mt][1][r] + blv[r] - 16.0f) * 6.528060436248779f;
          const float v   = (r11[r] + bfa[r]) + ro1;
          const float q   = clip8(rintf(v / 12.716455459594727f + 23.0f));
          pk |= ((int)q & 255) << (8*r);
        }
        *(int*)&lds[R2R_OFF + slot*260 + c0] = pk;
      }
    }
    __syncthreads();

    // ---- S4: dw2 (dil 3) from r2 ring -> B-frags (LUT requant) ----
    {
      const float d20 = wd2q[ch], d21 = wd2q[CIN+ch], d22 = wd2q[2*CIN+ch];
      const float bd2 = bd2q[ch];
      for (int s = 0; s < 16; ++s) {
        const int jr = hf*16 + ((s + tid) & 15);
        const int t = pt0 + jr;
        float cv[3];
#pragma unroll
        for (int li = 0; li < 3; ++li) {
          const int tt = t - 3*(2 - li);          // lags 6, 3, 0
          float c;
          if (tt < 0) c = -47.0f;
          else {
            const int sl = (tt + 3800) % 38;
            const int rv = (int)*(const signed char*)&lds[R2R_OFF + sl*260 + ch];
            c = (float)*(const signed char*)&lds[LUT_OFF + 128 + rv];
          }
          cv[li] = c;
        }
        const float v = fmaf(d20, cv[0], fmaf(d21, cv[1], fmaf(d22, cv[2], bd2)));
        const int ab = wofs_c + ((jr >> 4)*2048) + ((jr & 15)*16);
        const unsigned hp = cvtpk(v, v);
        const float hb = __builtin_bit_cast(float, hp << 16);
        const unsigned lp = cvtpk(v - hb, v - hb);
        *(unsigned short*)&lds[BF_OFF + ab]        = (unsigned short)hp;
        *(unsigned short*)&lds[BF_OFF + ab + 1024] = (unsigned short)lp;
      }
    }
    __syncthreads();

    // ---- G5: pw2 ----
#pragma unroll
    for (int mt = 0; mt < 2; ++mt) { acc[mt][0] = fz; acc[mt][1] = fz; }
    gemm_mfma(Awv + 2*262144, (const char*)lds + BF_OFF, lofs, acc);
    __syncthreads();
    // E5: +bias, leaky -> B-frags
#pragma unroll
    for (int mt = 0; mt < 2; ++mt) {
      const int c0 = c0m[mt];
      const float4 bb = *(const float4*)&bp2q[c0];
      const float bbv[4] = {bb.x, bb.y, bb.z, bb.w};
      const int ab0 = (c0 >> 5)*4096 + (((c0 & 31) >> 3)*16 + nn)*16 + (c0 & 7)*2;
#pragma unroll
      for (int nt = 0; nt < 2; ++nt) {
        float av[4];
#pragma unroll
        for (int r = 0; r < 4; ++r)
          av[r] = lrelu(acc[mt][nt][r] + bbv[r]);
        const unsigned h01 = cvtpk(av[0], av[1]);
        const unsigned h23 = cvtpk(av[2], av[3]);
        const float hb0 = __builtin_bit_cast(float, h01 << 16);
        const float hb1 = __builtin_bit_cast(float, h01 & 0xFFFF0000u);
        const float hb2 = __builtin_bit_cast(float, h23 << 16);
        const float hb3 = __builtin_bit_cast(float, h23 & 0xFFFF0000u);
        const unsigned l01 = cvtpk(av[0]-hb0, av[1]-hb1);
        const unsigned l23 = cvtpk(av[2]-hb2, av[3]-hb3);
        const int ab = ab0 + nt*2048;
        *(uint2*)&lds[BF_OFF + ab]        = make_uint2(h01, h23);
        *(uint2*)&lds[BF_OFF + ab + 1024] = make_uint2(l01, l23);
      }
    }
    __syncthreads();

    // ---- G6: lc2 ----
#pragma unroll
    for (int mt = 0; mt < 2; ++mt) { acc[mt][0] = fz; acc[mt][1] = fz; }
    gemm_mfma(Awv + 3*262144, (const char*)lds + BF_OFF, lofs, acc);
    // (G6->E6 sync removed: E6 writes only the c3 ring, whose prior-pass
    // reader S7 is >=4 barriers back; S7's B-frag WAR is the after-E6 sync)
    // E6: r3 = ro2 + q(re-read from r2 ring) -> resf; ci3 quant -> c3 ring
#pragma unroll
    for (int nt = 0; nt < 2; ++nt) {
      const int t = pt0 + nt*16 + nn;
      const int slot  = (t + 5000) % 50;
      const int slot2 = (t + 3800) % 38;
#pragma unroll
      for (int mt = 0; mt < 2; ++mt) {
        const int c0 = c0m[mt];
        const int pk2 = *(const int*)&lds[R2R_OFF + slot2*260 + c0];  // own E3 write
        const float4 bl = *(const float4*)&bl2q[c0];
        const float blv[4] = {bl.x, bl.y, bl.z, bl.w};
        int pk = 0;
#pragma unroll
        for (int r = 0; r < 4; ++r) {
          const float qold = (float)((signed char)((pk2 >> (8*r)) & 255));
          const float r3 = (acc[mt][nt][r] + blv[r]) + qold;
          resf[mt][nt][r] = r3;
          const float dq = (lrelu(r3) + 38.0f) * 4.458680152893066f;
          const float q  = clip8(rintf(dq / 4.458680152893066f - 38.0f));
          pk |= ((int)q & 255) << (8*r);
        }
        *(int*)&lds[C3R_OFF + slot*260 + c0] = pk;
      }
    }
    __syncthreads();

    if (pass == 0) continue;

    // ---- S7: dw3 (dil 9) from c3 ring -> B-frags ----
    {
      const float d30 = wd3q[ch], d31 = wd3q[CIN+ch], d32 = wd3q[2*CIN+ch];
      const float bd3 = bd3q[ch];
      for (int s = 0; s < 16; ++s) {
        const int jr = hf*16 + ((s + tid) & 15);
        const int t = pt0 + jr;
        float cv[3];
#pragma unroll
        for (int li = 0; li < 3; ++li) {
          const int tt = t - 9*(2 - li);          // lags 18, 9, 0
          float c;
          if (tt < 0) c = -38.0f;
          else {
            const int sl = (tt + 5000) % 50;
            c = (float)*(const signed char*)&lds[C3R_OFF + sl*260 + ch];
          }
          cv[li] = c;
        }
        const float v = fmaf(d30, cv[0], fmaf(d31, cv[1], fmaf(d32, cv[2], bd3)));
        const int ab = wofs_c + ((jr >> 4)*2048) + ((jr & 15)*16);
        const unsigned hp = cvtpk(v, v);
        const float hb = __builtin_bit_cast(float, hp << 16);
        const unsigned lp = cvtpk(v - hb, v - hb);
        *(unsigned short*)&lds[BF_OFF + ab]        = (unsigned short)hp;
        *(unsigned short*)&lds[BF_OFF + ab + 1024] = (unsigned short)lp;
      }
    }
    __syncthreads();

    // ---- G8: pw3 ----
#pragma unroll
    for (int mt = 0; mt < 2; ++mt) { acc[mt][0] = fz; acc[mt][1] = fz; }
    gemm_mfma(Awv + 4*262144, (const char*)lds + BF_OFF, lofs, acc);
    __syncthreads();
    // E8: +bias, leaky -> B-frags
#pragma unroll
    for (int mt = 0; mt < 2; ++mt) {
      const int c0 = c0m[mt];
      const float4 bb = *(const float4*)&bp3q[c0];
      const float bbv[4] = {bb.x, bb.y, bb.z, bb.w};
      const int ab0 = (c0 >> 5)*4096 + (((c0 & 31) >> 3)*16 + nn)*16 + (c0 & 7)*2;
#pragma unroll
      for (int nt = 0; nt < 2; ++nt) {
        float av[4];
#pragma unroll
        for (int r = 0; r < 4; ++r)
          av[r] = lrelu(acc[mt][nt][r] + bbv[r]);
        const unsigned h01 = cvtpk(av[0], av[1]);
        const unsigned h23 = cvtpk(av[2], av[3]);
        const float hb0 = __builtin_bit_cast(float, h01 << 16);
        const float hb1 = __builtin_bit_cast(float, h01 & 0xFFFF0000u);
        const float hb2 = __builtin_bit_cast(float, h23 << 16);
        const float hb3 = __builtin_bit_cast(float, h23 & 0xFFFF0000u);
        const unsigned l01 = cvtpk(av[0]-hb0, av[1]-hb1);
        const unsigned l23 = cvtpk(av[2]-hb2, av[3]-hb3);
        const int ab = ab0 + nt*2048;
        *(uint2*)&lds[BF_OFF + ab]        = make_uint2(h01, h23);
        *(uint2*)&lds[BF_OFF + ab + 1024] = make_uint2(l01, l23);
      }
    }
    __syncthreads();

    // ---- G9: lc3 + final epilogue -> out (nontemporal: write-once stream) ----
#pragma unroll
    for (int mt = 0; mt < 2; ++mt) { acc[mt][0] = fz; acc[mt][1] = fz; }
    gemm_mfma(Awv + 5*262144, (const char*)lds + BF_OFF, lofs, acc);
#pragma unroll
    for (int nt = 0; nt < 2; ++nt) {
      const int t = pt0 + nt*16 + nn;
      if (t < LOUT) {
#pragma unroll
        for (int mt = 0; mt < 2; ++mt) {
          const int c0 = c0m[mt];
          const float4 bl = *(const float4*)&bl3q[c0];
          const float blv[4] = {bl.x, bl.y, bl.z, bl.w};
          fx4 o;
#pragma unroll
          for (int r = 0; r < 4; ++r) {
            const float r4 = (acc[mt][nt][r] + blv[r]) + resf[mt][nt][r];
            o[r] = (lrelu(r4) + 34.0f) * 3.698859930038452f;
          }
          __builtin_nontemporal_store(o, (fx4*)&out[t*CIN + c0]);
        }
      }
    }
  }
}

extern "C" void kernel_launch(void* const* d_in, const int* in_sizes, int n_in,
                              void* d_out, int out_size, void* d_ws, size_t ws_size,
                              hipStream_t stream) {
  (void)in_sizes; (void)n_in; (void)out_size; (void)ws_size;
  const float* x       = (const float*)d_in[0];
  const float* w_first = (const float*)d_in[5];
  const float* b_first = (const float*)d_in[6];
  const float* w_dw1   = (const float*)d_in[7];
  const float* b_dw1   = (const float*)d_in[8];
  const float* w_pw1   = (const float*)d_in[9];
  const float* b_pw1   = (const float*)d_in[10];
  const float* w_lc1   = (const float*)d_in[11];
  const float* b_lc1   = (const float*)d_in[12];
  const float* w_dw2   = (const float*)d_in[13];
  const float* b_dw2   = (const float*)d_in[14];
  const float* w_pw2   = (const float*)d_in[15];
  const float* b_pw2   = (const float*)d_in[16];
  const float* w_lc2   = (const float*)d_in[17];
  const float* b_lc2   = (const float*)d_in[18];
  const float* w_dw3   = (const float*)d_in[19];
  const float* b_dw3   = (const float*)d_in[20];
  const float* w_pw3   = (const float*)d_in[21];
  const float* b_pw3   = (const float*)d_in[22];
  const float* w_lc3   = (const float*)d_in[23];
  const float* b_lc3   = (const float*)d_in[24];

  char* Apk = (char*)d_ws;                       // 6 x 262144 B = 1.5 MB

  pack_w<<<dim3(192), dim3(256), 0, stream>>>(w_pw1, w_lc1, w_pw2, w_lc2, w_pw3, w_lc3, Apk);
  enc_kernel<<<dim3(NBLK), dim3(512), 0, stream>>>(
      x, Apk, w_first, b_first,
      w_dw1, b_dw1, b_pw1, b_lc1,
      w_dw2, b_dw2, b_pw2, b_lc2,
      w_dw3, b_dw3, b_pw3, b_lc3,
      (float*)d_out);
}

// Round 12
// 720.811 us; speedup vs baseline: 1.3788x; 1.0566x over previous
//
#include <hip/hip_runtime.h>

// Fully fused quantized encoder, MFMA edition — 512-thread (8-wave) blocks.
// GEMMs: D[oc][frame] = W^T · act, bf16 hi/lo split (3 MFMAs, al*bl dropped ~2^-18).
// Weights pre-packed into d_ws in MFMA A-frag stream order (pack_w kernel).
// Activations live in LDS in MFMA B-frag stream order (hi 16KB + lo 16KB).
// r11 confirmed barriers are the lever (3 removed -> -46us, ~5.6us/instance:
// each barrier collapses cross-wave phase overlap). This rev removes 2 more:
//  (1) xw prefetch: next-pass x loaded to a register after G3, LDS-written
//      after the after-E3 barrier (orders vs E3's xw reads; S1(p+1) is >=6
//      barriers later). Pass-top barrier now only covers G9_prev/S1 WAR and
//      the pass-top HBM latency exposure is gone.
//  (2) S1+S1b fused with a ROLLING 3-register ci window (r10 done right:
//      r10's c[16] was +28 live regs -> spill; rolling adds ~5 -> under the
//      thrice-measured +10 threshold). Boundary convs computed locally with
//      the identical formula (identical bits). Kills barrier #2 and the ci1
//      LDS round-trip. Rotation lost -> S1b 2B stores ~8-way conflicted
//      (~100s of cycles, noise vs a 13k-cycle barrier).
// 12 barriers/pass (was 13; r9 had 16). Bit-identical (absmax==4.0 canary).
// Retained: 512thr/2blk/CU, pass-local weight loads via volatile-zero offset,
// gemm unroll-1, E3 mt-outer/k-inner, S4 LUT requant, E3->E6 resf handoff
// through r2 ring, nontemporal fx4 out stores, cvt_pk_bf16_f32.

#define CIN   256
#define LOUT  120000
#define TIN   600000
#define FB    128
#define NBLK  ((LOUT + FB - 1) / FB)   // 938

typedef float fx4 __attribute__((ext_vector_type(4)));
typedef short bx8 __attribute__((ext_vector_type(8)));

// ---- LDS map ----
#define BF_OFF   0        // 32768 B: B-frags (32 frames x 256 k), hi + lo bf16
#define R2R_OFF  50176    //  9880 B: r2 ring, 38 slots x 260 B (stride 260 = bank spread)
#define C3R_OFF  60056    // 13000 B: c3 ring, 50 slots x 260 B
#define XW_OFF   73056    //   704 B: x window (176 floats)
#define LUT_OFF  73760    //   256 B: S4 dequant->requant int8 LUT
#define LDS_SZ   74016    // (32768..50176 free since ci1 moved to registers)

__device__ __forceinline__ float lrelu(float v){ return v >= 0.0f ? v : 0.3f*v; }
__device__ __forceinline__ float clip8(float v){ return fminf(fmaxf(v, -128.0f), 127.0f); }
__device__ __forceinline__ unsigned short f2bf(float f){
  unsigned u = __builtin_bit_cast(unsigned, f);
  return (unsigned short)((u + 0x7FFFu + ((u >> 16) & 1u)) >> 16);  // RNE
}
__device__ __forceinline__ float bf2f(unsigned short h){
  unsigned u = ((unsigned)h) << 16;
  return __builtin_bit_cast(float, u);
}
// HW packed f32->bf16 (RNE, same result as f2bf): dst.lo=bf16(a), dst.hi=bf16(b)
__device__ __forceinline__ unsigned cvtpk(float a, float b){
  unsigned r;
  asm("v_cvt_pk_bf16_f32 %0, %1, %2" : "=v"(r) : "v"(a), "v"(b));
  return r;
}

// GEMM: acc[mt][nt] += Wmat-tile x B-act-tile, 3-term hi/lo split.
// Per-wave tile: M=32 (2 x 16-oc sub-tiles), N=32 frames, K=256.
// unroll 1: keeps live fragments ~32 VGPRs (fits the 64-arch-VGPR split).
__device__ __forceinline__ void gemm_mfma(const char* __restrict__ Aw,
                                          const char* __restrict__ Bf,
                                          int lofs, fx4 acc[2][2])
{
#pragma unroll 1
  for (int kk = 0; kk < 8; ++kk) {
    bx8 Bh0 = *(const bx8*)(Bf + kk*4096 +        lofs);
    bx8 Bl0 = *(const bx8*)(Bf + kk*4096 + 1024 + lofs);
    bx8 Bh1 = *(const bx8*)(Bf + kk*4096 + 2048 + lofs);
    bx8 Bl1 = *(const bx8*)(Bf + kk*4096 + 3072 + lofs);
#pragma unroll
    for (int mt = 0; mt < 2; ++mt) {
      bx8 Ah = *(const bx8*)(Aw + (mt*8 + kk)*2048 +        lofs);
      bx8 Al = *(const bx8*)(Aw + (mt*8 + kk)*2048 + 1024 + lofs);
      acc[mt][0] = __builtin_amdgcn_mfma_f32_16x16x32_bf16(Ah, Bh0, acc[mt][0], 0, 0, 0);
      acc[mt][0] = __builtin_amdgcn_mfma_f32_16x16x32_bf16(Al, Bh0, acc[mt][0], 0, 0, 0);
      acc[mt][0] = __builtin_amdgcn_mfma_f32_16x16x32_bf16(Ah, Bl0, acc[mt][0], 0, 0, 0);
      acc[mt][1] = __builtin_amdgcn_mfma_f32_16x16x32_bf16(Ah, Bh1, acc[mt][1], 0, 0, 0);
      acc[mt][1] = __builtin_amdgcn_mfma_f32_16x16x32_bf16(Al, Bh1, acc[mt][1], 0, 0, 0);
      acc[mt][1] = __builtin_amdgcn_mfma_f32_16x16x32_bf16(Ah, Bl1, acc[mt][1], 0, 0, 0);
    }
  }
}

// Pack 6 weight matrices [ic][oc] into A-frag stream (hi+lo bf16) in d_ws.
__global__ void pack_w(const float* __restrict__ w0, const float* __restrict__ w1,
                       const float* __restrict__ w2, const float* __restrict__ w3,
                       const float* __restrict__ w4, const float* __restrict__ w5,
                       char* __restrict__ Apk)
{
  const int l = blockIdx.x*256 + threadIdx.x;          // < 49152
  const int lane = l & 63, kk = (l >> 6) & 7, wm = (l >> 9) & 15, mat = l >> 13;
  const float* W = mat==0?w0 : mat==1?w1 : mat==2?w2 : mat==3?w3 : mat==4?w4 : w5;
  const int oc = wm*16 + (lane & 15);
  const int k0 = kk*32 + (lane >> 4)*8;
  unsigned short h[8], lo[8];
#pragma unroll
  for (int j = 0; j < 8; ++j) {
    const float v = W[(k0 + j)*CIN + oc];
    h[j]  = f2bf(v);
    lo[j] = f2bf(v - bf2f(h[j]));
  }
  char* base = Apk + mat*262144 + (wm*8 + kk)*2048 + lane*16;
  *(ushort4*)(base)        = make_ushort4(h[0],  h[1],  h[2],  h[3]);
  *(ushort4*)(base + 8)    = make_ushort4(h[4],  h[5],  h[6],  h[7]);
  *(ushort4*)(base + 1024) = make_ushort4(lo[0], lo[1], lo[2], lo[3]);
  *(ushort4*)(base + 1032) = make_ushort4(lo[4], lo[5], lo[6], lo[7]);
}

__launch_bounds__(512, 4)
__global__ void enc_kernel(const float* __restrict__ x,
                           const char* __restrict__ Apk,
                           const float* __restrict__ w_first, const float* __restrict__ b_first,
                           const float* __restrict__ w_dw1, const float* __restrict__ b_dw1,
                           const float* __restrict__ b_pw1, const float* __restrict__ b_lc1,
                           const float* __restrict__ w_dw2, const float* __restrict__ b_dw2,
                           const float* __restrict__ b_pw2, const float* __restrict__ b_lc2,
                           const float* __restrict__ w_dw3, const float* __restrict__ b_dw3,
                           const float* __restrict__ b_pw3, const float* __restrict__ b_lc3,
                           float* __restrict__ out)
{
  __shared__ __align__(16) char lds[LDS_SZ];
  const int tid  = threadIdx.x;        // 0..511
  const int lane = tid & 63;
  const int wv   = tid >> 6;           // 0..7
  const int qq   = lane >> 4;
  const int nn   = lane & 15;
  const int lofs = lane * 16;
  const int ch   = tid & 255;          // channel for S-phases
  const int hf   = tid >> 8;           // frame-half (0/1)
  const int t0   = blockIdx.x * FB;
  const fx4 fz = {0.0f, 0.0f, 0.0f, 0.0f};
  const char* Awv = Apk + wv*32768;    // per-wave A base (32 oc slice)

  // LICM blocker: volatile zero, re-read each pass. Compiler cannot prove
  // z==0, so any load whose address involves z stays inside the pass loop.
  volatile int vz = 0;

  // S4 dequant->requant LUT: pure function of the ring int8; computed with
  // the EXACT op sequence S4 used inline -> bit-identical. Written once;
  // the prologue barrier + >=2 pass barriers precede the first S4 read.
  if (tid < 256) {
    const float r  = (float)(tid - 128);
    const float dq = (lrelu(r) + 47.0f) * 5.548006534576416f;
    const float c  = clip8(rintf(dq / 5.548006534576416f - 47.0f));
    *(signed char*)&lds[LUT_OFF + tid] = (signed char)(int)c;
  }

  // Prologue xw for pass 0
  if (tid < 176) {
    const int gx = 5*(t0 - 32) - 15 + tid;
    *(float*)&lds[XW_OFF + tid*4] = (gx >= 0 && gx < TIN) ? x[gx] : 0.0f;
  }
  __syncthreads();

  // frag-write constants for channel c = ch (k-dim position)
  const int wofs_c = (ch >> 5)*4096 + (((ch & 31) >> 3)*16)*16 + (ch & 7)*2;

  int c0m[2];
#pragma unroll
  for (int mt = 0; mt < 2; ++mt) c0m[mt] = wv*32 + mt*16 + qq*4;

  fx4 acc[2][2];

  for (int pass = 0; pass < 5; ++pass) {
    const int pt0 = t0 - 32 + pass*32;
    const int xbase = 5*pt0 - 15;

    const int z = vz;                  // fresh opaque 0 each pass
    const float* wfq  = w_first + z; const float* bfq  = b_first + z;
    const float* wd1q = w_dw1 + z;   const float* bd1q = b_dw1 + z;
    const float* wd2q = w_dw2 + z;   const float* bd2q = b_dw2 + z;
    const float* wd3q = w_dw3 + z;   const float* bd3q = b_dw3 + z;
    const float* bp1q = b_pw1 + z;   const float* bl1q = b_lc1 + z;
    const float* bp2q = b_pw2 + z;   const float* bl2q = b_lc2 + z;
    const float* bp3q = b_pw3 + z;   const float* bl3q = b_lc3 + z;

    // resf lives E6 -> G9 only (E3's value is re-read from the r2 LDS ring).
    float resf[2][2][4];

    if (pass > 0) __syncthreads();     // G9_prev B-frag reads vs S1 writes

    // ---- S1 fused (conv + leaky + dw1 -> B-frags), rolling 3-reg ci window.
    //      Each half computes its own boundary convs (identical formula ->
    //      identical bits vs the old cross-thread ci1 values). ----
    {
      float wf[10];
#pragma unroll
      for (int k = 0; k < 10; ++k) wf[k] = wfq[k*CIN + ch];
      const float bfv = bfq[ch];
      const float d10 = wd1q[ch], d11 = wd1q[CIN+ch], d12 = wd1q[2*CIN+ch];
      const float bd1 = bd1q[ch];
      const int j0 = hf * 16;
      float cm2, cm1;
#pragma unroll
      for (int p2 = 0; p2 < 2; ++p2) {
        const int j = j0 + p2;
        float a = 0.0f;
#pragma unroll
        for (int k = 0; k < 10; ++k)
          a = fmaf(*(const float*)&lds[XW_OFF + (5*j + k)*4], wf[k], a);
        const float ci = (pt0 + j - 2 < 0) ? 0.0f : lrelu(a + bfv);
        const float cv = __builtin_bit_cast(float, cvtpk(ci, ci) << 16);
        if (p2 == 0) cm2 = cv; else cm1 = cv;
      }
#pragma unroll 2
      for (int s = 0; s < 16; ++s) {
        const int j = j0 + s + 2;
        float a = 0.0f;
#pragma unroll
        for (int k = 0; k < 10; ++k)
          a = fmaf(*(const float*)&lds[XW_OFF + (5*j + k)*4], wf[k], a);
        const float ci = (pt0 + j - 2 < 0) ? 0.0f : lrelu(a + bfv);
        const float c0v = __builtin_bit_cast(float, cvtpk(ci, ci) << 16);
        const float v = fmaf(d10, cm2, fmaf(d11, cm1, fmaf(d12, c0v, bd1)));
        const int jr = j0 + s;
        const int ab = wofs_c + ((jr >> 4)*2048) + ((jr & 15)*16);
        const unsigned hp = cvtpk(v, v);
        const float hb = __builtin_bit_cast(float, hp << 16);
        const unsigned lp = cvtpk(v - hb, v - hb);
        *(unsigned short*)&lds[BF_OFF + ab]        = (unsigned short)hp;
        *(unsigned short*)&lds[BF_OFF + ab + 1024] = (unsigned short)lp;
        cm2 = cm1; cm1 = c0v;
      }
    }
    __syncthreads();

    // ---- G2: pw1 ----
#pragma unroll
    for (int mt = 0; mt < 2; ++mt) { acc[mt][0] = fz; acc[mt][1] = fz; }
    gemm_mfma(Awv + 0*262144, (const char*)lds + BF_OFF, lofs, acc);
    __syncthreads();
    // E2: +bias, quantize(17.63,-67), leaky -> B-frags
#pragma unroll
    for (int mt = 0; mt < 2; ++mt) {
      const int c0 = c0m[mt];
      const float4 bb = *(const float4*)&bp1q[c0];
      const float bbv[4] = {bb.x, bb.y, bb.z, bb.w};
      const int ab0 = (c0 >> 5)*4096 + (((c0 & 31) >> 3)*16 + nn)*16 + (c0 & 7)*2;
#pragma unroll
      for (int nt = 0; nt < 2; ++nt) {
        float av[4];
#pragma unroll
        for (int r = 0; r < 4; ++r) {
          const float h  = acc[mt][nt][r] + bbv[r];
          const float qv = clip8(rintf(h / 17.62967872619629f + 67.0f));
          av[r] = lrelu(qv);
        }
        const unsigned h01 = cvtpk(av[0], av[1]);
        const unsigned h23 = cvtpk(av[2], av[3]);
        const float hb0 = __builtin_bit_cast(float, h01 << 16);
        const float hb1 = __builtin_bit_cast(float, h01 & 0xFFFF0000u);
        const float hb2 = __builtin_bit_cast(float, h23 << 16);
        const float hb3 = __builtin_bit_cast(float, h23 & 0xFFFF0000u);
        const unsigned l01 = cvtpk(av[0]-hb0, av[1]-hb1);
        const unsigned l23 = cvtpk(av[2]-hb2, av[3]-hb3);
        const int ab = ab0 + nt*2048;
        *(uint2*)&lds[BF_OFF + ab]        = make_uint2(h01, h23);
        *(uint2*)&lds[BF_OFF + ab + 1024] = make_uint2(l01, l23);
      }
    }
    __syncthreads();

    // ---- G3: lc1 ----
#pragma unroll
    for (int mt = 0; mt < 2; ++mt) { acc[mt][0] = fz; acc[mt][1] = fz; }
    gemm_mfma(Awv + 1*262144, (const char*)lds + BF_OFF, lofs, acc);

    // xw prefetch for pass+1: global->register here (hides under E3),
    // LDS write after the after-E3 barrier (ordered vs E3's xw reads).
    float xnext = 0.0f;
    if (pass < 4 && tid < 176) {
      const int gx = xbase + 160 + tid;
      xnext = (gx >= 0 && gx < TIN) ? x[gx] : 0.0f;
    }

    // (G3->E3 sync removed: E3 touches only the r2 ring, whose prior-pass
    // readers are >=5 barriers back; S4's B-frag WAR is the after-E3 sync)
    // E3: ro1 dequant + r1(recompute, mt-outer/k-inner) -> quantize -> r2 ring
#pragma unroll
    for (int mt = 0; mt < 2; ++mt) {
      const int c0 = c0m[mt];
      float r10[4] = {0.0f, 0.0f, 0.0f, 0.0f};   // nt=0 accumulators
      float r11[4] = {0.0f, 0.0f, 0.0f, 0.0f};   // nt=1 accumulators
#pragma unroll 2
      for (int k = 0; k < 10; ++k) {
        const float4 wk = *(const float4*)&wfq[k*CIN + c0];
        const float x0 = *(const float*)&lds[XW_OFF + (5*nn        + 10 + k)*4];
        const float x1 = *(const float*)&lds[XW_OFF + (5*(16 + nn) + 10 + k)*4];
        r10[0] = fmaf(x0, wk.x, r10[0]); r10[1] = fmaf(x0, wk.y, r10[1]);
        r10[2] = fmaf(x0, wk.z, r10[2]); r10[3] = fmaf(x0, wk.w, r10[3]);
        r11[0] = fmaf(x1, wk.x, r11[0]); r11[1] = fmaf(x1, wk.y, r11[1]);
        r11[2] = fmaf(x1, wk.z, r11[2]); r11[3] = fmaf(x1, wk.w, r11[3]);
      }
      const float4 bl = *(const float4*)&bl1q[c0];
      const float4 bf = *(const float4*)&bfq[c0];
      const float blv[4] = {bl.x, bl.y, bl.z, bl.w};
      const float bfa[4] = {bf.x, bf.y, bf.z, bf.w};
      // nt = 0
      {
        const int t = pt0 + nn;
        const int slot = (t + 3800) % 38;
        int pk = 0;
#pragma unroll
        for (int r = 0; r < 4; ++r) {
          const float ro1 = (acc[mt][0][r] + blv[r] - 16.0f) * 6.528060436248779f;
          const float v   = (r10[r] + bfa[r]) + ro1;
          const float q   = clip8(rintf(v / 12.716455459594727f + 23.0f));
          pk |= ((int)q & 255) << (8*r);
        }
        *(int*)&lds[R2R_OFF + slot*260 + c0] = pk;
      }
      // nt = 1
      {
        const int t = pt0 + 16 + nn;
        const int slot = (t + 3800) % 38;
        int pk = 0;
#pragma unroll
        for (int r = 0; r < 4; ++r) {
          const float ro1 = (acc[mt][1][r] + blv[r] - 16.0f) * 6.528060436248779f;
          const float v   = (r11[r] + bfa[r]) + ro1;
          const float q   = clip8(rintf(v / 12.716455459594727f + 23.0f));
          pk |= ((int)q & 255) << (8*r);
        }
        *(int*)&lds[R2R_OFF + slot*260 + c0] = pk;
      }
    }
    __syncthreads();

    // xw(p+1) LDS write: E3(p)'s xw reads are behind the barrier above;
    // next reader (S1 of pass p+1) is >=6 barriers ahead.
    if (pass < 4 && tid < 176) *(float*)&lds[XW_OFF + tid*4] = xnext;

    // ---- S4: dw2 (dil 3) from r2 ring -> B-frags (LUT requant) ----
    {
      const float d20 = wd2q[ch], d21 = wd2q[CIN+ch], d22 = wd2q[2*CIN+ch];
      const float bd2 = bd2q[ch];
      for (int s = 0; s < 16; ++s) {
        const int jr = hf*16 + ((s + tid) & 15);
        const int t = pt0 + jr;
        float cv[3];
#pragma unroll
        for (int li = 0; li < 3; ++li) {
          const int tt = t - 3*(2 - li);          // lags 6, 3, 0
          float c;
          if (tt < 0) c = -47.0f;
          else {
            const int sl = (tt + 3800) % 38;
            const int rv = (int)*(const signed char*)&lds[R2R_OFF + sl*260 + ch];
            c = (float)*(const signed char*)&lds[LUT_OFF + 128 + rv];
          }
          cv[li] = c;
        }
        const float v = fmaf(d20, cv[0], fmaf(d21, cv[1], fmaf(d22, cv[2], bd2)));
        const int ab = wofs_c + ((jr >> 4)*2048) + ((jr & 15)*16);
        const unsigned hp = cvtpk(v, v);
        const float hb = __builtin_bit_cast(float, hp << 16);
        const unsigned lp = cvtpk(v - hb, v - hb);
        *(unsigned short*)&lds[BF_OFF + ab]        = (unsigned short)hp;
        *(unsigned short*)&lds[BF_OFF + ab + 1024] = (unsigned short)lp;
      }
    }
    __syncthreads();

    // ---- G5: pw2 ----
#pragma unroll
    for (int mt = 0; mt < 2; ++mt) { acc[mt][0] = fz; acc[mt][1] = fz; }
    gemm_mfma(Awv + 2*262144, (const char*)lds + BF_OFF, lofs, acc);
    __syncthreads();
    // E5: +bias, leaky -> B-frags
#pragma unroll
    for (int mt = 0; mt < 2; ++mt) {
      const int c0 = c0m[mt];
      const float4 bb = *(const float4*)&bp2q[c0];
      const float bbv[4] = {bb.x, bb.y, bb.z, bb.w};
      const int ab0 = (c0 >> 5)*4096 + (((c0 & 31) >> 3)*16 + nn)*16 + (c0 & 7)*2;
#pragma unroll
      for (int nt = 0; nt < 2; ++nt) {
        float av[4];
#pragma unroll
        for (int r = 0; r < 4; ++r)
          av[r] = lrelu(acc[mt][nt][r] + bbv[r]);
        const unsigned h01 = cvtpk(av[0], av[1]);
        const unsigned h23 = cvtpk(av[2], av[3]);
        const float hb0 = __builtin_bit_cast(float, h01 << 16);
        const float hb1 = __builtin_bit_cast(float, h01 & 0xFFFF0000u);
        const float hb2 = __builtin_bit_cast(float, h23 << 16);
        const float hb3 = __builtin_bit_cast(float, h23 & 0xFFFF0000u);
        const unsigned l01 = cvtpk(av[0]-hb0, av[1]-hb1);
        const unsigned l23 = cvtpk(av[2]-hb2, av[3]-hb3);
        const int ab = ab0 + nt*2048;
        *(uint2*)&lds[BF_OFF + ab]        = make_uint2(h01, h23);
        *(uint2*)&lds[BF_OFF + ab + 1024] = make_uint2(l01, l23);
      }
    }
    __syncthreads();

    // ---- G6: lc2 ----
#pragma unroll
    for (int mt = 0; mt < 2; ++mt) { acc[mt][0] = fz; acc[mt][1] = fz; }
    gemm_mfma(Awv + 3*262144, (const char*)lds + BF_OFF, lofs, acc);
    // (G6->E6 sync removed: E6 writes only the c3 ring, whose prior-pass
    // reader S7 is >=4 barriers back; S7's B-frag WAR is the after-E6 sync)
    // E6: r3 = ro2 + q(re-read from r2 ring) -> resf; ci3 quant -> c3 ring
#pragma unroll
    for (int nt = 0; nt < 2; ++nt) {
      const int t = pt0 + nt*16 + nn;
      const int slot  = (t + 5000) % 50;
      const int slot2 = (t + 3800) % 38;
#pragma unroll
      for (int mt = 0; mt < 2; ++mt) {
        const int c0 = c0m[mt];
        const int pk2 = *(const int*)&lds[R2R_OFF + slot2*260 + c0];  // own E3 write
        const float4 bl = *(const float4*)&bl2q[c0];
        const float blv[4] = {bl.x, bl.y, bl.z, bl.w};
        int pk = 0;
#pragma unroll
        for (int r = 0; r < 4; ++r) {
          const float qold = (float)((signed char)((pk2 >> (8*r)) & 255));
          const float r3 = (acc[mt][nt][r] + blv[r]) + qold;
          resf[mt][nt][r] = r3;
          const float dq = (lrelu(r3) + 38.0f) * 4.458680152893066f;
          const float q  = clip8(rintf(dq / 4.458680152893066f - 38.0f));
          pk |= ((int)q & 255) << (8*r);
        }
        *(int*)&lds[C3R_OFF + slot*260 + c0] = pk;
      }
    }
    __syncthreads();

    if (pass == 0) continue;

    // ---- S7: dw3 (dil 9) from c3 ring -> B-frags ----
    {
      const float d30 = wd3q[ch], d31 = wd3q[CIN+ch], d32 = wd3q[2*CIN+ch];
      const float bd3 = bd3q[ch];
      for (int s = 0; s < 16; ++s) {
        const int jr = hf*16 + ((s + tid) & 15);
        const int t = pt0 + jr;
        float cv[3];
#pragma unroll
        for (int li = 0; li < 3; ++li) {
          const int tt = t - 9*(2 - li);          // lags 18, 9, 0
          float c;
          if (tt < 0) c = -38.0f;
          else {
            const int sl = (tt + 5000) % 50;
            c = (float)*(const signed char*)&lds[C3R_OFF + sl*260 + ch];
          }
          cv[li] = c;
        }
        const float v = fmaf(d30, cv[0], fmaf(d31, cv[1], fmaf(d32, cv[2], bd3)));
        const int ab = wofs_c + ((jr >> 4)*2048) + ((jr & 15)*16);
        const unsigned hp = cvtpk(v, v);
        const float hb = __builtin_bit_cast(float, hp << 16);
        const unsigned lp = cvtpk(v - hb, v - hb);
        *(unsigned short*)&lds[BF_OFF + ab]        = (unsigned short)hp;
        *(unsigned short*)&lds[BF_OFF + ab + 1024] = (unsigned short)lp;
      }
    }
    __syncthreads();

    // ---- G8: pw3 ----
#pragma unroll
    for (int mt = 0; mt < 2; ++mt) { acc[mt][0] = fz; acc[mt][1] = fz; }
    gemm_mfma(Awv + 4*262144, (const char*)lds + BF_OFF, lofs, acc);
    __syncthreads();
    // E8: +bias, leaky -> B-frags
#pragma unroll
    for (int mt = 0; mt < 2; ++mt) {
      const int c0 = c0m[mt];
      const float4 bb = *(const float4*)&bp3q[c0];
      const float bbv[4] = {bb.x, bb.y, bb.z, bb.w};
      const int ab0 = (c0 >> 5)*4096 + (((c0 & 31) >> 3)*16 + nn)*16 + (c0 & 7)*2;
#pragma unroll
      for (int nt = 0; nt < 2; ++nt) {
        float av[4];
#pragma unroll
        for (int r = 0; r < 4; ++r)
          av[r] = lrelu(acc[mt][nt][r] + bbv[r]);
        const unsigned h01 = cvtpk(av[0], av[1]);
        const unsigned h23 = cvtpk(av[2], av[3]);
        const float hb0 = __builtin_bit_cast(float, h01 << 16);
        const float hb1 = __builtin_bit_cast(float, h01 & 0xFFFF0000u);
        const float hb2 = __builtin_bit_cast(float, h23 << 16);
        const float hb3 = __builtin_bit_cast(float, h23 & 0xFFFF0000u);
        const unsigned l01 = cvtpk(av[0]-hb0, av[1]-hb1);
        const unsigned l23 = cvtpk(av[2]-hb2, av[3]-hb3);
        const int ab = ab0 + nt*2048;
        *(uint2*)&lds[BF_OFF + ab]        = make_uint2(h01, h23);
        *(uint2*)&lds[BF_OFF + ab + 1024] = make_uint2(l01, l23);
      }
    }
    __syncthreads();

    // ---- G9: lc3 + final epilogue -> out (nontemporal: write-once stream) ----
#pragma unroll
    for (int mt = 0; mt < 2; ++mt) { acc[mt][0] = fz; acc[mt][1] = fz; }
    gemm_mfma(Awv + 5*262144, (const char*)lds + BF_OFF, lofs, acc);
#pragma unroll
    for (int nt = 0; nt < 2; ++nt) {
      const int t = pt0 + nt*16 + nn;
      if (t < LOUT) {
#pragma unroll
        for (int mt = 0; mt < 2; ++mt) {
          const int c0 = c0m[mt];
          const float4 bl = *(const float4*)&bl3q[c0];
          const float blv[4] = {bl.x, bl.y, bl.z, bl.w};
          fx4 o;
#pragma unroll
          for (int r = 0; r < 4; ++r) {
            const float r4 = (acc[mt][nt][r] + blv[r]) + resf[mt][nt][r];
            o[r] = (lrelu(r4) + 34.0f) * 3.698859930038452f;
          }
          __builtin_nontemporal_store(o, (fx4*)&out[t*CIN + c0]);
        }
      }
    }
  }
}

extern "C" void kernel_launch(void* const* d_in, const int* in_sizes, int n_in,
                              void* d_out, int out_size, void* d_ws, size_t ws_size,
                              hipStream_t stream) {
  (void)in_sizes; (void)n_in; (void)out_size; (void)ws_size;
  const float* x       = (const float*)d_in[0];
  const float* w_first = (const float*)d_in[5];
  const float* b_first = (const float*)d_in[6];
  const float* w_dw1   = (const float*)d_in[7];
  const float* b_dw1   = (const float*)d_in[8];
  const float* w_pw1   = (const float*)d_in[9];
  const float* b_pw1   = (const float*)d_in[10];
  const float* w_lc1   = (const float*)d_in[11];
  const float* b_lc1   = (const float*)d_in[12];
  const float* w_dw2   = (const float*)d_in[13];
  const float* b_dw2   = (const float*)d_in[14];
  const float* w_pw2   = (const float*)d_in[15];
  const float* b_pw2   = (const float*)d_in[16];
  const float* w_lc2   = (const float*)d_in[17];
  const float* b_lc2   = (const float*)d_in[18];
  const float* w_dw3   = (const float*)d_in[19];
  const float* b_dw3   = (const float*)d_in[20];
  const float* w_pw3   = (const float*)d_in[21];
  const float* b_pw3   = (const float*)d_in[22];
  const float* w_lc3   = (const float*)d_in[23];
  const float* b_lc3   = (const float*)d_in[24];

  char* Apk = (char*)d_ws;                       // 6 x 262144 B = 1.5 MB

  pack_w<<<dim3(192), dim3(256), 0, stream>>>(w_pw1, w_lc1, w_pw2, w_lc2, w_pw3, w_lc3, Apk);
  enc_kernel<<<dim3(NBLK), dim3(512), 0, stream>>>(
      x, Apk, w_first, b_first,
      w_dw1, b_dw1, b_pw1, b_lc1,
      w_dw2, b_dw2, b_pw2, b_lc2,
      w_dw3, b_dw3, b_pw3, b_lc3,
      (float*)d_out);
}